// Round 10
// baseline (58.799 us; speedup 1.0000x reference)
//
#include <hip/hip_runtime.h>
#include <hip/hip_bf16.h>

// GFNet global filter: out = irfft2( rfft2(x) * W ), ortho norm, 14x14 spatial.
// x: (B=256, N=196, C=768) f32 ; W: (14, 8, C, 2) f32 ; out: (B, 196, C) f32.
//
// R10: packed-FP32 (v_pk_fma_f32) arithmetic via ext_vector_type(2) +
// __builtin_elementwise_fma. Pairing:
//   phases A/D: across the wave's two rows (r0, r1)
//   phases B/W/C: across (re, im) of each complex value, with pre-swizzled
//     [ed.y, -ed.x]-style copies so cross-terms are single pk-fmas.
// Memory structure identical to R9 (best, 56.8us): bf16-packed single-round
// LDS transposes, 3 barriers, 28672 B buffer, non-temporal output stores
// (out write-stream was evicting x from the 256MB LLC; nt stores fixed it).
//
// __launch_bounds__(512,3): (512,8)/(512,6) forced VGPR 32/40 -> scratch
// spills (WRITE_SIZE exceeded output bytes). Tripwire: WRITE_SIZE must stay
// == 150.5 MB.

static constexpr int CB     = 64;
static constexpr int NT     = 512;
static constexpr int CTILES = 768 / CB;   // 12

typedef float f2 __attribute__((ext_vector_type(2)));

// cos/sin(2*pi*k/14)
static constexpr float C14[14] = {
     1.0f,
     0.90096886790241915f,  0.62348980185873359f,  0.22252093395631445f,
    -0.22252093395631434f, -0.62348980185873348f, -0.90096886790241915f,
    -1.0f,
    -0.90096886790241926f, -0.62348980185873371f, -0.22252093395631456f,
     0.22252093395631423f,  0.62348980185873337f,  0.90096886790241904f
};
static constexpr float S14[14] = {
     0.0f,
     0.43388373911755812f,  0.78183148246802980f,  0.97492791218182362f,
     0.97492791218182362f,  0.78183148246802991f,  0.43388373911755823f,
     0.0f,
    -0.43388373911755806f, -0.78183148246802958f, -0.97492791218182362f,
    -0.97492791218182373f, -0.78183148246802991f, -0.43388373911755834f
};

__device__ __forceinline__ f2 mk2(float a, float b) { f2 r; r.x = a; r.y = b; return r; }
__device__ __forceinline__ f2 sp2(float a)          { f2 r; r.x = a; r.y = a; return r; }
// acc += a * scalar  (single v_pk_fma_f32)
__device__ __forceinline__ f2 fma2(f2 a, float c, f2 acc) {
    return __builtin_elementwise_fma(a, sp2(c), acc);
}

__device__ __forceinline__ uint32_t pk_bf16(float re, float im) {
    union { __hip_bfloat162 h2; uint32_t u; } cv;
    cv.h2 = __float22bfloat162_rn(make_float2(re, im));
    return cv.u;
}
__device__ __forceinline__ f2 up_bf16(uint32_t v) {
    return mk2(__uint_as_float(v << 16), __uint_as_float(v & 0xffff0000u));
}

__global__ __launch_bounds__(NT, 3) void gfnet_filter(
    const float* __restrict__ x,
    const float* __restrict__ wgt,
    float* __restrict__ out)
{
    // 28672 B union buffer, packed bf16 complex:
    //   G round: [h=0..13][u=0..7][64]   (u=0,7 carry im=0)
    //   P round: [row=0..13][v=0..7][64]
    __shared__ uint32_t T[14 * 8 * 64];

    const int bid = blockIdx.x;
    const int b   = bid / CTILES;
    const int ct  = bid - b * CTILES;
    const int c0  = ct * CB;
    const int tid = threadIdx.x;
    const int wv  = tid >> 6;
    const int ln  = tid & 63;
    const bool two = (wv < 6);
    const int r0 = wv;          // rows handled in phases A/D
    const int r1 = wv + 8;

    const float* xb = x + (size_t)b * 196 * 768 + c0 + ln;

    // ---------------- phase A: rfft along w, rows r0/r1 packed in f2 lanes ----------------
    f2 Ar[8], Ai[7];            // Ai index 1..6 used
    {
        f2 v[14];
        #pragma unroll
        for (int w = 0; w < 14; ++w) {
            v[w].x = xb[(size_t)(r0 * 14 + w) * 768];
            v[w].y = 0.f;
        }
        if (two) {
            #pragma unroll
            for (int w = 0; w < 14; ++w) v[w].y = xb[(size_t)(r1 * 14 + w) * 768];
        }
        f2 s[7], d[7];
        #pragma unroll
        for (int j = 1; j <= 6; ++j) { s[j] = v[j] + v[14 - j]; d[j] = v[j] - v[14 - j]; }
        const f2 p = v[0] + v[7], q = v[0] - v[7];
        Ar[0] = p + s[1] + s[2] + s[3] + s[4] + s[5] + s[6];
        Ar[7] = q - s[1] + s[2] - s[3] + s[4] - s[5] + s[6];
        #pragma unroll
        for (int u = 1; u <= 6; ++u) {
            f2 re = (u & 1) ? q : p;
            f2 im = sp2(0.f);
            #pragma unroll
            for (int j = 1; j <= 6; ++j) {
                re = fma2(s[j],  C14[(u * j) % 14], re);
                im = fma2(d[j], -S14[(u * j) % 14], im);
            }
            Ar[u] = re; Ai[u] = im;
        }
    }

    // ---------------- G transpose (packed bf16, single round) ----------------
    #pragma unroll
    for (int u = 0; u < 8; ++u)
        T[(r0 * 8 + u) * 64 + ln] =
            pk_bf16(Ar[u].x, (u >= 1 && u <= 6) ? Ai[u].x : 0.f);
    if (two) {
        #pragma unroll
        for (int u = 0; u < 8; ++u)
            T[(r1 * 8 + u) * 64 + ln] =
                pk_bf16(Ar[u].y, (u >= 1 && u <= 6) ? Ai[u].y : 0.f);
    }

    // hoist weight loads: issue before the barrier so latency overlaps the wait
    f2 w2[14];
    {
        const float2* wb = reinterpret_cast<const float2*>(wgt) + (size_t)wv * 768 + c0 + ln;
        #pragma unroll
        for (int k = 0; k < 14; ++k) {
            const float2 t = wb[(size_t)k * (8 * 768)];
            w2[k] = mk2(t.x, t.y);
        }
    }

    __syncthreads();                    // bar1: G visible

    f2 g[14];                           // [re, im] per h, column u = wv
    #pragma unroll
    for (int h = 0; h < 14; ++h) g[h] = up_bf16(T[(h * 8 + wv) * 64 + ln]);

    // ---------------- phase B: a[k] = FFT_h(g), radix-2 + pairing, complex-packed ----------------
    f2 es[3], eds[3], os[3], ods[3];
    #pragma unroll
    for (int i = 0; i < 3; ++i) {
        int j = 2 * (i + 1);
        es[i] = g[j] + g[14 - j];
        f2 ed = g[j] - g[14 - j];
        eds[i] = mk2(ed.y, -ed.x);      // E += eds*s2 -> re += edi*s2, im -= edr*s2
        j = 2 * i + 1;
        os[i] = g[j] + g[14 - j];
        f2 od = g[j] - g[14 - j];
        ods[i] = mk2(od.y, -od.x);
    }
    f2 E[7], O[7];
    E[0] = g[0] + es[0] + es[1] + es[2];
    O[0] = g[7] + os[0] + os[1] + os[2];
    #pragma unroll
    for (int k = 1; k <= 6; ++k) {
        f2 e = g[0];
        #pragma unroll
        for (int i = 0; i < 3; ++i) {
            const int j = 2 * (i + 1);
            e = fma2(es[i],  C14[(j * k) % 14], e);
            e = fma2(eds[i], S14[(j * k) % 14], e);
        }
        E[k] = e;
        f2 o = (k & 1) ? -g[7] : g[7];
        #pragma unroll
        for (int i = 0; i < 3; ++i) {
            const int j = 2 * i + 1;
            o = fma2(os[i],  C14[(j * k) % 14], o);
            o = fma2(ods[i], S14[(j * k) % 14], o);
        }
        O[k] = o;
    }

    // ---------------- weight multiply: H[k] = a[k] * w[k], complex-packed ----------------
    f2 H[14];
    #pragma unroll
    for (int k = 0; k < 7; ++k) {
        const f2 a_ = E[k] + O[k];
        const f2 b_ = E[k] - O[k];
        const f2 wsA = mk2(-w2[k].y, w2[k].x);
        const f2 wsB = mk2(-w2[k + 7].y, w2[k + 7].x);
        H[k]     = __builtin_elementwise_fma(w2[k],     sp2(a_.x), wsA * sp2(a_.y));
        H[k + 7] = __builtin_elementwise_fma(w2[k + 7], sp2(b_.x), wsB * sp2(b_.y));
    }

    // ---------------- phase C: P = IFFT_h(H), radix-2 + pairing, complex-packed ----------------
    f2 qs[3], qds[3], rs[3], rds[3];
    #pragma unroll
    for (int i = 0; i < 3; ++i) {
        int j = 2 * (i + 1);
        qs[i] = H[j] + H[14 - j];
        f2 qd = H[j] - H[14 - j];
        qds[i] = mk2(-qd.y, qd.x);      // Q += qds*s2 -> re -= qdi*s2, im += qdr*s2
        j = 2 * i + 1;
        rs[i] = H[j] + H[14 - j];
        f2 rd = H[j] - H[14 - j];
        rds[i] = mk2(-rd.y, rd.x);
    }
    f2 Q[7], R[7];
    Q[0] = H[0] + qs[0] + qs[1] + qs[2];
    R[0] = H[7] + rs[0] + rs[1] + rs[2];
    #pragma unroll
    for (int m = 1; m <= 6; ++m) {
        f2 qq = H[0];
        #pragma unroll
        for (int i = 0; i < 3; ++i) {
            const int j = 2 * (i + 1);
            qq = fma2(qs[i],  C14[(j * m) % 14], qq);
            qq = fma2(qds[i], S14[(j * m) % 14], qq);
        }
        Q[m] = qq;
        f2 rr = (m & 1) ? -H[7] : H[7];
        #pragma unroll
        for (int i = 0; i < 3; ++i) {
            const int j = 2 * i + 1;
            rr = fma2(rs[i],  C14[(j * m) % 14], rr);
            rr = fma2(rds[i], S14[(j * m) % 14], rr);
        }
        R[m] = rr;
    }

    __syncthreads();                    // bar2: all G reads done (convergent: placed
                                        // right after the long B/W/C compute)

    // ---------------- P transpose (packed bf16, single round) ----------------
    #pragma unroll
    for (int m = 0; m < 7; ++m) {
        const f2 pa = Q[m] + R[m];
        const f2 pb = Q[m] - R[m];
        T[(m * 8 + wv) * 64 + ln]       = pk_bf16(pa.x, pa.y);
        T[((m + 7) * 8 + wv) * 64 + ln] = pk_bf16(pb.x, pb.y);
    }
    __syncthreads();                    // bar3: P visible

    // ---------------- phase D: inverse rfft along w, rows r0/r1 packed, nt stores ----------------
    float* ob = out + (size_t)b * 196 * 768 + c0 + ln;
    {
        f2 a0[8], b0v[7];               // a0 = re over [r0,r1]; b0v = im over [r0,r1]
        #pragma unroll
        for (int v = 0; v < 8; ++v) {
            const f2 p0 = up_bf16(T[(r0 * 8 + v) * 64 + ln]);
            f2 p1 = sp2(0.f);
            if (two) p1 = up_bf16(T[(r1 * 8 + v) * 64 + ln]);
            const float beta = (v == 0 || v == 7) ? (1.0f / 196.0f) : (2.0f / 196.0f);
            a0[v] = mk2(p0.x, p1.x) * sp2(beta);
            if (v >= 1 && v <= 6) b0v[v] = mk2(p0.y, p1.y) * sp2(2.0f / 196.0f);
        }
        const f2 pp = a0[0] + a0[7], qq = a0[0] - a0[7];
        const f2 o0 = pp + a0[1] + a0[2] + a0[3] + a0[4] + a0[5] + a0[6];
        const f2 o7 = qq - a0[1] + a0[2] - a0[3] + a0[4] - a0[5] + a0[6];
        __builtin_nontemporal_store(o0.x, &ob[(size_t)(r0 * 14 + 0) * 768]);
        __builtin_nontemporal_store(o7.x, &ob[(size_t)(r0 * 14 + 7) * 768]);
        if (two) {
            __builtin_nontemporal_store(o0.y, &ob[(size_t)(r1 * 14 + 0) * 768]);
            __builtin_nontemporal_store(o7.y, &ob[(size_t)(r1 * 14 + 7) * 768]);
        }
        #pragma unroll
        for (int wp = 1; wp <= 6; ++wp) {
            f2 t1 = (wp & 1) ? qq : pp;
            f2 t2 = sp2(0.f);
            #pragma unroll
            for (int v = 1; v <= 6; ++v) {
                t1 = fma2(a0[v],  C14[(v * wp) % 14], t1);
                t2 = fma2(b0v[v], S14[(v * wp) % 14], t2);
            }
            const f2 om = t1 - t2;      // row (.., wp)
            const f2 op = t1 + t2;      // row (.., 14-wp)
            __builtin_nontemporal_store(om.x, &ob[(size_t)(r0 * 14 + wp) * 768]);
            __builtin_nontemporal_store(op.x, &ob[(size_t)(r0 * 14 + 14 - wp) * 768]);
            if (two) {
                __builtin_nontemporal_store(om.y, &ob[(size_t)(r1 * 14 + wp) * 768]);
                __builtin_nontemporal_store(op.y, &ob[(size_t)(r1 * 14 + 14 - wp) * 768]);
            }
        }
    }
}

extern "C" void kernel_launch(void* const* d_in, const int* in_sizes, int n_in,
                              void* d_out, int out_size, void* d_ws, size_t ws_size,
                              hipStream_t stream) {
    const float* x   = (const float*)d_in[0];
    const float* wgt = (const float*)d_in[1];
    float*       o   = (float*)d_out;

    const int B = in_sizes[0] / (196 * 768);   // 256
    dim3 grid(B * CTILES), block(NT);
    gfnet_filter<<<grid, block, 0, stream>>>(x, wgt, o);
}

// Round 11
// 56.757 us; speedup vs baseline: 1.0360x; 1.0360x over previous
//
#include <hip/hip_runtime.h>
#include <hip/hip_bf16.h>

// GFNet global filter: out = irfft2( rfft2(x) * W ), ortho norm, 14x14 spatial.
// x: (B=256, N=196, C=768) f32 ; W: (14, 8, C, 2) f32 ; out: (B, 196, C) f32.
//
// R11 hybrid: phases A/D use packed-f32 (v_pk_fma_f32) across the wave's two
// rows (r0,r1) — pure inst halving, ILP structure unchanged (R10 validated).
// Phases B/W/C stay SCALAR re/im (R9 form): R10's (re,im)-packing there cut
// chain count in the longest phase and grew timed stall 14.7->27.2us.
// Memory structure = R9 (best, 56.8us): bf16-packed single-round LDS
// transposes, 3 barriers, 28672 B buffer, non-temporal output stores (the
// out-write stream was evicting x from the 256MB LLC).
//
// __launch_bounds__(512,3): (512,8)/(512,6) forced VGPR 32/40 -> scratch
// spills (WRITE_SIZE exceeded output bytes). Tripwire: WRITE_SIZE == 150.5MB.

static constexpr int CB     = 64;
static constexpr int NT     = 512;
static constexpr int CTILES = 768 / CB;   // 12

typedef float f2 __attribute__((ext_vector_type(2)));

// cos/sin(2*pi*k/14)
static constexpr float C14[14] = {
     1.0f,
     0.90096886790241915f,  0.62348980185873359f,  0.22252093395631445f,
    -0.22252093395631434f, -0.62348980185873348f, -0.90096886790241915f,
    -1.0f,
    -0.90096886790241926f, -0.62348980185873371f, -0.22252093395631456f,
     0.22252093395631423f,  0.62348980185873337f,  0.90096886790241904f
};
static constexpr float S14[14] = {
     0.0f,
     0.43388373911755812f,  0.78183148246802980f,  0.97492791218182362f,
     0.97492791218182362f,  0.78183148246802991f,  0.43388373911755823f,
     0.0f,
    -0.43388373911755806f, -0.78183148246802958f, -0.97492791218182362f,
    -0.97492791218182373f, -0.78183148246802991f, -0.43388373911755834f
};

__device__ __forceinline__ f2 mk2(float a, float b) { f2 r; r.x = a; r.y = b; return r; }
__device__ __forceinline__ f2 sp2(float a)          { f2 r; r.x = a; r.y = a; return r; }
__device__ __forceinline__ f2 fma2(f2 a, float c, f2 acc) {
    return __builtin_elementwise_fma(a, sp2(c), acc);
}

__device__ __forceinline__ uint32_t pk_bf16(float re, float im) {
    union { __hip_bfloat162 h2; uint32_t u; } cv;
    cv.h2 = __float22bfloat162_rn(make_float2(re, im));
    return cv.u;
}
__device__ __forceinline__ f2 up_bf16(uint32_t v) {
    return mk2(__uint_as_float(v << 16), __uint_as_float(v & 0xffff0000u));
}

__global__ __launch_bounds__(NT, 3) void gfnet_filter(
    const float* __restrict__ x,
    const float* __restrict__ wgt,
    float* __restrict__ out)
{
    // 28672 B union buffer, packed bf16 complex:
    //   G round: [h=0..13][u=0..7][64]   (u=0,7 carry im=0)
    //   P round: [row=0..13][v=0..7][64]
    __shared__ uint32_t T[14 * 8 * 64];

    const int bid = blockIdx.x;
    const int b   = bid / CTILES;
    const int ct  = bid - b * CTILES;
    const int c0  = ct * CB;
    const int tid = threadIdx.x;
    const int wv  = tid >> 6;
    const int ln  = tid & 63;
    const bool two = (wv < 6);
    const int r0 = wv;          // rows handled in phases A/D
    const int r1 = wv + 8;

    const float* xb = x + (size_t)b * 196 * 768 + c0 + ln;

    // ---------------- phase A: rfft along w, rows r0/r1 packed in f2 lanes ----------------
    f2 Ar[8], Ai[7];            // Ai index 1..6 used
    {
        f2 v[14];
        #pragma unroll
        for (int w = 0; w < 14; ++w) {
            v[w].x = xb[(size_t)(r0 * 14 + w) * 768];
            v[w].y = 0.f;
        }
        if (two) {
            #pragma unroll
            for (int w = 0; w < 14; ++w) v[w].y = xb[(size_t)(r1 * 14 + w) * 768];
        }
        f2 s[7], d[7];
        #pragma unroll
        for (int j = 1; j <= 6; ++j) { s[j] = v[j] + v[14 - j]; d[j] = v[j] - v[14 - j]; }
        const f2 p = v[0] + v[7], q = v[0] - v[7];
        Ar[0] = p + s[1] + s[2] + s[3] + s[4] + s[5] + s[6];
        Ar[7] = q - s[1] + s[2] - s[3] + s[4] - s[5] + s[6];
        #pragma unroll
        for (int u = 1; u <= 6; ++u) {
            f2 re = (u & 1) ? q : p;
            f2 im = sp2(0.f);
            #pragma unroll
            for (int j = 1; j <= 6; ++j) {
                re = fma2(s[j],  C14[(u * j) % 14], re);
                im = fma2(d[j], -S14[(u * j) % 14], im);
            }
            Ar[u] = re; Ai[u] = im;
        }
    }

    // ---------------- G transpose (packed bf16, single round) ----------------
    #pragma unroll
    for (int u = 0; u < 8; ++u)
        T[(r0 * 8 + u) * 64 + ln] =
            pk_bf16(Ar[u].x, (u >= 1 && u <= 6) ? Ai[u].x : 0.f);
    if (two) {
        #pragma unroll
        for (int u = 0; u < 8; ++u)
            T[(r1 * 8 + u) * 64 + ln] =
                pk_bf16(Ar[u].y, (u >= 1 && u <= 6) ? Ai[u].y : 0.f);
    }

    // hoist weight loads: issue before the barrier so latency overlaps the wait
    float wr[14], wi[14];
    {
        const float2* wb = reinterpret_cast<const float2*>(wgt) + (size_t)wv * 768 + c0 + ln;
        #pragma unroll
        for (int k = 0; k < 14; ++k) {
            const float2 t = wb[(size_t)k * (8 * 768)];
            wr[k] = t.x; wi[k] = t.y;
        }
    }

    __syncthreads();                    // bar1: G visible

    float gr[14], gi[14];
    #pragma unroll
    for (int h = 0; h < 14; ++h) {
        const f2 t = up_bf16(T[(h * 8 + wv) * 64 + ln]);
        gr[h] = t.x; gi[h] = t.y;
    }

    // ---------------- phase B: a[k] = FFT_h(g), radix-2 + pairing (scalar) ----------------
    float esr[3], esi[3], edr[3], edi[3], osr[3], osi[3], odr[3], odi[3];
    #pragma unroll
    for (int i = 0; i < 3; ++i) {
        int j = 2 * (i + 1);
        esr[i] = gr[j] + gr[14 - j]; esi[i] = gi[j] + gi[14 - j];
        edr[i] = gr[j] - gr[14 - j]; edi[i] = gi[j] - gi[14 - j];
        j = 2 * i + 1;
        osr[i] = gr[j] + gr[14 - j]; osi[i] = gi[j] + gi[14 - j];
        odr[i] = gr[j] - gr[14 - j]; odi[i] = gi[j] - gi[14 - j];
    }
    float Ekr[7], Eki[7], Okr[7], Oki[7];
    Ekr[0] = gr[0] + esr[0] + esr[1] + esr[2];
    Eki[0] = gi[0] + esi[0] + esi[1] + esi[2];
    Okr[0] = gr[7] + osr[0] + osr[1] + osr[2];
    Oki[0] = gi[7] + osi[0] + osi[1] + osi[2];
    #pragma unroll
    for (int k = 1; k <= 6; ++k) {
        float er = gr[0], ei = gi[0];
        #pragma unroll
        for (int i = 0; i < 3; ++i) {
            const int j = 2 * (i + 1);
            const float c = C14[(j * k) % 14], s2 = S14[(j * k) % 14];
            er = fmaf(esr[i], c, er); er = fmaf(edi[i],  s2, er);
            ei = fmaf(esi[i], c, ei); ei = fmaf(edr[i], -s2, ei);
        }
        Ekr[k] = er; Eki[k] = ei;
        float onr = (k & 1) ? -gr[7] : gr[7];
        float oni = (k & 1) ? -gi[7] : gi[7];
        #pragma unroll
        for (int i = 0; i < 3; ++i) {
            const int j = 2 * i + 1;
            const float c = C14[(j * k) % 14], s2 = S14[(j * k) % 14];
            onr = fmaf(osr[i], c, onr); onr = fmaf(odi[i],  s2, onr);
            oni = fmaf(osi[i], c, oni); oni = fmaf(odr[i], -s2, oni);
        }
        Okr[k] = onr; Oki[k] = oni;
    }

    // ---------------- weight multiply: H[k] = a[k] * w[k] (scalar) ----------------
    float Hr[14], Hi[14];
    #pragma unroll
    for (int k = 0; k < 7; ++k) {
        const float ar = Ekr[k] + Okr[k], ai = Eki[k] + Oki[k];
        const float br = Ekr[k] - Okr[k], bi = Eki[k] - Oki[k];
        Hr[k]     = fmaf(ar, wr[k],     -(ai * wi[k]));
        Hi[k]     = fmaf(ar, wi[k],       ai * wr[k]);
        Hr[k + 7] = fmaf(br, wr[k + 7], -(bi * wi[k + 7]));
        Hi[k + 7] = fmaf(br, wi[k + 7],   bi * wr[k + 7]);
    }

    // ---------------- phase C: P = IFFT_h(H), radix-2 + pairing (scalar) ----------------
    float qsr[3], qsi[3], qdr[3], qdi[3], rsr[3], rsi[3], rdr[3], rdi[3];
    #pragma unroll
    for (int i = 0; i < 3; ++i) {
        int j = 2 * (i + 1);
        qsr[i] = Hr[j] + Hr[14 - j]; qsi[i] = Hi[j] + Hi[14 - j];
        qdr[i] = Hr[j] - Hr[14 - j]; qdi[i] = Hi[j] - Hi[14 - j];
        j = 2 * i + 1;
        rsr[i] = Hr[j] + Hr[14 - j]; rsi[i] = Hi[j] + Hi[14 - j];
        rdr[i] = Hr[j] - Hr[14 - j]; rdi[i] = Hi[j] - Hi[14 - j];
    }
    float Qr[7], Qi[7], Rr[7], Ri[7];
    Qr[0] = Hr[0] + qsr[0] + qsr[1] + qsr[2];
    Qi[0] = Hi[0] + qsi[0] + qsi[1] + qsi[2];
    Rr[0] = Hr[7] + rsr[0] + rsr[1] + rsr[2];
    Ri[0] = Hi[7] + rsi[0] + rsi[1] + rsi[2];
    #pragma unroll
    for (int m = 1; m <= 6; ++m) {
        float qr = Hr[0], qi2 = Hi[0];
        #pragma unroll
        for (int i = 0; i < 3; ++i) {
            const int j = 2 * (i + 1);
            const float c = C14[(j * m) % 14], s2 = S14[(j * m) % 14];
            qr  = fmaf(qsr[i], c, qr);  qr  = fmaf(qdi[i], -s2, qr);
            qi2 = fmaf(qsi[i], c, qi2); qi2 = fmaf(qdr[i],  s2, qi2);
        }
        Qr[m] = qr; Qi[m] = qi2;
        float rr = (m & 1) ? -Hr[7] : Hr[7];
        float ri2 = (m & 1) ? -Hi[7] : Hi[7];
        #pragma unroll
        for (int i = 0; i < 3; ++i) {
            const int j = 2 * i + 1;
            const float c = C14[(j * m) % 14], s2 = S14[(j * m) % 14];
            rr  = fmaf(rsr[i], c, rr);  rr  = fmaf(rdi[i], -s2, rr);
            ri2 = fmaf(rsi[i], c, ri2); ri2 = fmaf(rdr[i],  s2, ri2);
        }
        Rr[m] = rr; Ri[m] = ri2;
    }

    __syncthreads();                    // bar2: all G reads done (convergent)

    // ---------------- P transpose (packed bf16, single round) ----------------
    #pragma unroll
    for (int m = 0; m < 7; ++m) {
        T[(m * 8 + wv) * 64 + ln]       = pk_bf16(Qr[m] + Rr[m], Qi[m] + Ri[m]);
        T[((m + 7) * 8 + wv) * 64 + ln] = pk_bf16(Qr[m] - Rr[m], Qi[m] - Ri[m]);
    }
    __syncthreads();                    // bar3: P visible

    // ---------------- phase D: inverse rfft along w, rows r0/r1 packed, nt stores ----------------
    float* ob = out + (size_t)b * 196 * 768 + c0 + ln;
    {
        f2 a0[8], b0v[7];               // a0 = re over [r0,r1]; b0v = im over [r0,r1]
        #pragma unroll
        for (int v = 0; v < 8; ++v) {
            const f2 p0 = up_bf16(T[(r0 * 8 + v) * 64 + ln]);
            f2 p1 = sp2(0.f);
            if (two) p1 = up_bf16(T[(r1 * 8 + v) * 64 + ln]);
            const float beta = (v == 0 || v == 7) ? (1.0f / 196.0f) : (2.0f / 196.0f);
            a0[v] = mk2(p0.x, p1.x) * sp2(beta);
            if (v >= 1 && v <= 6) b0v[v] = mk2(p0.y, p1.y) * sp2(2.0f / 196.0f);
        }
        const f2 pp = a0[0] + a0[7], qq = a0[0] - a0[7];
        const f2 o0 = pp + a0[1] + a0[2] + a0[3] + a0[4] + a0[5] + a0[6];
        const f2 o7 = qq - a0[1] + a0[2] - a0[3] + a0[4] - a0[5] + a0[6];
        __builtin_nontemporal_store(o0.x, &ob[(size_t)(r0 * 14 + 0) * 768]);
        __builtin_nontemporal_store(o7.x, &ob[(size_t)(r0 * 14 + 7) * 768]);
        if (two) {
            __builtin_nontemporal_store(o0.y, &ob[(size_t)(r1 * 14 + 0) * 768]);
            __builtin_nontemporal_store(o7.y, &ob[(size_t)(r1 * 14 + 7) * 768]);
        }
        #pragma unroll
        for (int wp = 1; wp <= 6; ++wp) {
            f2 t1 = (wp & 1) ? qq : pp;
            f2 t2 = sp2(0.f);
            #pragma unroll
            for (int v = 1; v <= 6; ++v) {
                t1 = fma2(a0[v],  C14[(v * wp) % 14], t1);
                t2 = fma2(b0v[v], S14[(v * wp) % 14], t2);
            }
            const f2 om = t1 - t2;      // row (.., wp)
            const f2 op = t1 + t2;      // row (.., 14-wp)
            __builtin_nontemporal_store(om.x, &ob[(size_t)(r0 * 14 + wp) * 768]);
            __builtin_nontemporal_store(op.x, &ob[(size_t)(r0 * 14 + 14 - wp) * 768]);
            if (two) {
                __builtin_nontemporal_store(om.y, &ob[(size_t)(r1 * 14 + wp) * 768]);
                __builtin_nontemporal_store(op.y, &ob[(size_t)(r1 * 14 + 14 - wp) * 768]);
            }
        }
    }
}

extern "C" void kernel_launch(void* const* d_in, const int* in_sizes, int n_in,
                              void* d_out, int out_size, void* d_ws, size_t ws_size,
                              hipStream_t stream) {
    const float* x   = (const float*)d_in[0];
    const float* wgt = (const float*)d_in[1];
    float*       o   = (float*)d_out;

    const int B = in_sizes[0] / (196 * 768);   // 256
    dim3 grid(B * CTILES), block(NT);
    gfnet_filter<<<grid, block, 0, stream>>>(x, wgt, o);
}

// Round 12
// 56.382 us; speedup vs baseline: 1.0429x; 1.0067x over previous
//
#include <hip/hip_runtime.h>
#include <hip/hip_bf16.h>

// GFNet global filter: out = irfft2( rfft2(x) * W ), ortho norm, 14x14 spatial.
// x: (B=256, N=196, C=768) f32 ; W: (14, 8, C, 2) f32 ; out: (B, 196, C) f32.
//
// R12: 2-tile software pipeline per block. Tiles (b, ct) and (b+B/2, ct):
//  - t1 x-loads issued before bar1 -> latency hidden under t0's B/W/C
//  - t0 D+stores placed between t1's G-transpose and bar5 -> drain overlapped
//  - weights loaded once (same ct => same weights for both tiles)
//  - 7 barriers / 2 tiles; single 28672 B LDS buffer (bar4 = P-read/G-write hazard)
// Rationale: R9/R10/R11 showed wall (56.8us) is insensitive to VALU issue count
// (busy 31.6-42us all gave 56.8-58.8) -> latency/overlap-bound, not issue-bound.
// Memory structure from R9: bf16-packed single-round transposes, nt stores
// (out write-stream was evicting x from the 256MB LLC).
//
// __launch_bounds__(512,2): empirical VGPR budget ~128 (pattern 256/N: (512,8)
// ->32, (512,6)->40, (512,3)->85). Peak live here ~110-120.
// Spill tripwire: WRITE_SIZE must equal 150.5 MB.

static constexpr int CB     = 64;
static constexpr int NT     = 512;
static constexpr int CTILES = 768 / CB;   // 12

typedef float f2 __attribute__((ext_vector_type(2)));

// cos/sin(2*pi*k/14)
static constexpr float C14[14] = {
     1.0f,
     0.90096886790241915f,  0.62348980185873359f,  0.22252093395631445f,
    -0.22252093395631434f, -0.62348980185873348f, -0.90096886790241915f,
    -1.0f,
    -0.90096886790241926f, -0.62348980185873371f, -0.22252093395631456f,
     0.22252093395631423f,  0.62348980185873337f,  0.90096886790241904f
};
static constexpr float S14[14] = {
     0.0f,
     0.43388373911755812f,  0.78183148246802980f,  0.97492791218182362f,
     0.97492791218182362f,  0.78183148246802991f,  0.43388373911755823f,
     0.0f,
    -0.43388373911755806f, -0.78183148246802958f, -0.97492791218182362f,
    -0.97492791218182373f, -0.78183148246802991f, -0.43388373911755834f
};

__device__ __forceinline__ f2 mk2(float a, float b) { f2 r; r.x = a; r.y = b; return r; }
__device__ __forceinline__ f2 sp2(float a)          { f2 r; r.x = a; r.y = a; return r; }
__device__ __forceinline__ f2 fma2(f2 a, float c, f2 acc) {
    return __builtin_elementwise_fma(a, sp2(c), acc);
}

__device__ __forceinline__ uint32_t pk_bf16(float re, float im) {
    union { __hip_bfloat162 h2; uint32_t u; } cv;
    cv.h2 = __float22bfloat162_rn(make_float2(re, im));
    return cv.u;
}
__device__ __forceinline__ f2 up_bf16(uint32_t v) {
    return mk2(__uint_as_float(v << 16), __uint_as_float(v & 0xffff0000u));
}

// ---------------- phase A: rfft along w, rows packed in f2 lanes ----------------
__device__ __forceinline__ void phaseA(const f2 v[14], f2 Ar[8], f2 Ai[7]) {
    f2 s[7], d[7];
    #pragma unroll
    for (int j = 1; j <= 6; ++j) { s[j] = v[j] + v[14 - j]; d[j] = v[j] - v[14 - j]; }
    const f2 p = v[0] + v[7], q = v[0] - v[7];
    Ar[0] = p + s[1] + s[2] + s[3] + s[4] + s[5] + s[6];
    Ar[7] = q - s[1] + s[2] - s[3] + s[4] - s[5] + s[6];
    #pragma unroll
    for (int u = 1; u <= 6; ++u) {
        f2 re = (u & 1) ? q : p;
        f2 im = sp2(0.f);
        #pragma unroll
        for (int j = 1; j <= 6; ++j) {
            re = fma2(s[j],  C14[(u * j) % 14], re);
            im = fma2(d[j], -S14[(u * j) % 14], im);
        }
        Ar[u] = re; Ai[u] = im;
    }
}

// ---------------- G transpose write (packed bf16) ----------------
__device__ __forceinline__ void gT_write(uint32_t* T, const f2 Ar[8], const f2 Ai[7],
                                         int r0, int r1, bool two, int ln) {
    #pragma unroll
    for (int u = 0; u < 8; ++u)
        T[(r0 * 8 + u) * 64 + ln] = pk_bf16(Ar[u].x, (u >= 1 && u <= 6) ? Ai[u].x : 0.f);
    if (two) {
        #pragma unroll
        for (int u = 0; u < 8; ++u)
            T[(r1 * 8 + u) * 64 + ln] = pk_bf16(Ar[u].y, (u >= 1 && u <= 6) ? Ai[u].y : 0.f);
    }
}

// ---------------- phases B + W + C (scalar re/im, radix-2 + pairing) ----------------
__device__ __forceinline__ void phaseBWC(const float gr[14], const float gi[14],
                                         const float wr[14], const float wi[14],
                                         float Qr[7], float Qi[7], float Rr[7], float Ri[7]) {
    float esr[3], esi[3], edr[3], edi[3], osr[3], osi[3], odr[3], odi[3];
    #pragma unroll
    for (int i = 0; i < 3; ++i) {
        int j = 2 * (i + 1);
        esr[i] = gr[j] + gr[14 - j]; esi[i] = gi[j] + gi[14 - j];
        edr[i] = gr[j] - gr[14 - j]; edi[i] = gi[j] - gi[14 - j];
        j = 2 * i + 1;
        osr[i] = gr[j] + gr[14 - j]; osi[i] = gi[j] + gi[14 - j];
        odr[i] = gr[j] - gr[14 - j]; odi[i] = gi[j] - gi[14 - j];
    }
    float Ekr[7], Eki[7], Okr[7], Oki[7];
    Ekr[0] = gr[0] + esr[0] + esr[1] + esr[2];
    Eki[0] = gi[0] + esi[0] + esi[1] + esi[2];
    Okr[0] = gr[7] + osr[0] + osr[1] + osr[2];
    Oki[0] = gi[7] + osi[0] + osi[1] + osi[2];
    #pragma unroll
    for (int k = 1; k <= 6; ++k) {
        float er = gr[0], ei = gi[0];
        #pragma unroll
        for (int i = 0; i < 3; ++i) {
            const int j = 2 * (i + 1);
            const float c = C14[(j * k) % 14], s2 = S14[(j * k) % 14];
            er = fmaf(esr[i], c, er); er = fmaf(edi[i],  s2, er);
            ei = fmaf(esi[i], c, ei); ei = fmaf(edr[i], -s2, ei);
        }
        Ekr[k] = er; Eki[k] = ei;
        float onr = (k & 1) ? -gr[7] : gr[7];
        float oni = (k & 1) ? -gi[7] : gi[7];
        #pragma unroll
        for (int i = 0; i < 3; ++i) {
            const int j = 2 * i + 1;
            const float c = C14[(j * k) % 14], s2 = S14[(j * k) % 14];
            onr = fmaf(osr[i], c, onr); onr = fmaf(odi[i],  s2, onr);
            oni = fmaf(osi[i], c, oni); oni = fmaf(odr[i], -s2, oni);
        }
        Okr[k] = onr; Oki[k] = oni;
    }
    float Hr[14], Hi[14];
    #pragma unroll
    for (int k = 0; k < 7; ++k) {
        const float ar = Ekr[k] + Okr[k], ai = Eki[k] + Oki[k];
        const float br = Ekr[k] - Okr[k], bi = Eki[k] - Oki[k];
        Hr[k]     = fmaf(ar, wr[k],     -(ai * wi[k]));
        Hi[k]     = fmaf(ar, wi[k],       ai * wr[k]);
        Hr[k + 7] = fmaf(br, wr[k + 7], -(bi * wi[k + 7]));
        Hi[k + 7] = fmaf(br, wi[k + 7],   bi * wr[k + 7]);
    }
    float qsr[3], qsi[3], qdr[3], qdi[3], rsr[3], rsi[3], rdr[3], rdi[3];
    #pragma unroll
    for (int i = 0; i < 3; ++i) {
        int j = 2 * (i + 1);
        qsr[i] = Hr[j] + Hr[14 - j]; qsi[i] = Hi[j] + Hi[14 - j];
        qdr[i] = Hr[j] - Hr[14 - j]; qdi[i] = Hi[j] - Hi[14 - j];
        j = 2 * i + 1;
        rsr[i] = Hr[j] + Hr[14 - j]; rsi[i] = Hi[j] + Hi[14 - j];
        rdr[i] = Hr[j] - Hr[14 - j]; rdi[i] = Hi[j] - Hi[14 - j];
    }
    Qr[0] = Hr[0] + qsr[0] + qsr[1] + qsr[2];
    Qi[0] = Hi[0] + qsi[0] + qsi[1] + qsi[2];
    Rr[0] = Hr[7] + rsr[0] + rsr[1] + rsr[2];
    Ri[0] = Hi[7] + rsi[0] + rsi[1] + rsi[2];
    #pragma unroll
    for (int m = 1; m <= 6; ++m) {
        float qr = Hr[0], qi2 = Hi[0];
        #pragma unroll
        for (int i = 0; i < 3; ++i) {
            const int j = 2 * (i + 1);
            const float c = C14[(j * m) % 14], s2 = S14[(j * m) % 14];
            qr  = fmaf(qsr[i], c, qr);  qr  = fmaf(qdi[i], -s2, qr);
            qi2 = fmaf(qsi[i], c, qi2); qi2 = fmaf(qdr[i],  s2, qi2);
        }
        Qr[m] = qr; Qi[m] = qi2;
        float rr = (m & 1) ? -Hr[7] : Hr[7];
        float ri2 = (m & 1) ? -Hi[7] : Hi[7];
        #pragma unroll
        for (int i = 0; i < 3; ++i) {
            const int j = 2 * i + 1;
            const float c = C14[(j * m) % 14], s2 = S14[(j * m) % 14];
            rr  = fmaf(rsr[i], c, rr);  rr  = fmaf(rdi[i], -s2, rr);
            ri2 = fmaf(rsi[i], c, ri2); ri2 = fmaf(rdr[i],  s2, ri2);
        }
        Rr[m] = rr; Ri[m] = ri2;
    }
}

// ---------------- P transpose write (packed bf16) ----------------
__device__ __forceinline__ void pT_write(uint32_t* T, const float Qr[7], const float Qi[7],
                                         const float Rr[7], const float Ri[7], int wv, int ln) {
    #pragma unroll
    for (int m = 0; m < 7; ++m) {
        T[(m * 8 + wv) * 64 + ln]       = pk_bf16(Qr[m] + Rr[m], Qi[m] + Ri[m]);
        T[((m + 7) * 8 + wv) * 64 + ln] = pk_bf16(Qr[m] - Rr[m], Qi[m] - Ri[m]);
    }
}

// ---------------- P read (into regs) ----------------
__device__ __forceinline__ void pRead(const uint32_t* T, f2 a0[8], f2 b0v[7],
                                      int r0, int r1, bool two, int ln) {
    #pragma unroll
    for (int v = 0; v < 8; ++v) {
        const f2 p0 = up_bf16(T[(r0 * 8 + v) * 64 + ln]);
        f2 p1 = sp2(0.f);
        if (two) p1 = up_bf16(T[(r1 * 8 + v) * 64 + ln]);
        const float beta = (v == 0 || v == 7) ? (1.0f / 196.0f) : (2.0f / 196.0f);
        a0[v] = mk2(p0.x, p1.x) * sp2(beta);
        if (v >= 1 && v <= 6) b0v[v] = mk2(p0.y, p1.y) * sp2(2.0f / 196.0f);
    }
}

// ---------------- phase D math + nt stores ----------------
__device__ __forceinline__ void phaseD(const f2 a0[8], const f2 b0v[7], float* ob,
                                       int r0, int r1, bool two) {
    const f2 pp = a0[0] + a0[7], qq = a0[0] - a0[7];
    const f2 o0 = pp + a0[1] + a0[2] + a0[3] + a0[4] + a0[5] + a0[6];
    const f2 o7 = qq - a0[1] + a0[2] - a0[3] + a0[4] - a0[5] + a0[6];
    __builtin_nontemporal_store(o0.x, &ob[(size_t)(r0 * 14 + 0) * 768]);
    __builtin_nontemporal_store(o7.x, &ob[(size_t)(r0 * 14 + 7) * 768]);
    if (two) {
        __builtin_nontemporal_store(o0.y, &ob[(size_t)(r1 * 14 + 0) * 768]);
        __builtin_nontemporal_store(o7.y, &ob[(size_t)(r1 * 14 + 7) * 768]);
    }
    #pragma unroll
    for (int wp = 1; wp <= 6; ++wp) {
        f2 t1 = (wp & 1) ? qq : pp;
        f2 t2 = sp2(0.f);
        #pragma unroll
        for (int v = 1; v <= 6; ++v) {
            t1 = fma2(a0[v],  C14[(v * wp) % 14], t1);
            t2 = fma2(b0v[v], S14[(v * wp) % 14], t2);
        }
        const f2 om = t1 - t2;
        const f2 op = t1 + t2;
        __builtin_nontemporal_store(om.x, &ob[(size_t)(r0 * 14 + wp) * 768]);
        __builtin_nontemporal_store(op.x, &ob[(size_t)(r0 * 14 + 14 - wp) * 768]);
        if (two) {
            __builtin_nontemporal_store(om.y, &ob[(size_t)(r1 * 14 + wp) * 768]);
            __builtin_nontemporal_store(op.y, &ob[(size_t)(r1 * 14 + 14 - wp) * 768]);
        }
    }
}

__global__ __launch_bounds__(NT, 2) void gfnet_filter(
    const float* __restrict__ x,
    const float* __restrict__ wgt,
    float* __restrict__ out,
    int bhalf)
{
    __shared__ uint32_t T[14 * 8 * 64];   // 28672 B, packed bf16 complex

    const int bid = blockIdx.x;
    const int bb  = bid / CTILES;         // 0 .. bhalf-1
    const int ct  = bid - bb * CTILES;
    const int c0  = ct * CB;
    const int tid = threadIdx.x;
    const int wv  = tid >> 6;
    const int ln  = tid & 63;
    const bool two = (wv < 6);
    const int r0 = wv;
    const int r1 = wv + 8;

    const size_t toff = (size_t)bhalf * 196 * 768;
    const float* xb0 = x + (size_t)bb * 196 * 768 + c0 + ln;
    const float* xb1 = xb0 + toff;
    float* ob0 = out + (size_t)bb * 196 * 768 + c0 + ln;
    float* ob1 = ob0 + toff;

    // ---- tile0 x loads ----
    f2 v0[14];
    #pragma unroll
    for (int w = 0; w < 14; ++w) {
        v0[w].x = xb0[(size_t)(r0 * 14 + w) * 768];
        v0[w].y = 0.f;
    }
    if (two) {
        #pragma unroll
        for (int w = 0; w < 14; ++w) v0[w].y = xb0[(size_t)(r1 * 14 + w) * 768];
    }

    // ---- weights (shared by both tiles: same ct, same wv) ----
    float wr[14], wi[14];
    {
        const float2* wb = reinterpret_cast<const float2*>(wgt) + (size_t)wv * 768 + c0 + ln;
        #pragma unroll
        for (int k = 0; k < 14; ++k) {
            const float2 t = wb[(size_t)k * (8 * 768)];
            wr[k] = t.x; wi[k] = t.y;
        }
    }

    // ---- tile0: A + G transpose ----
    f2 Ar[8], Ai[7];
    phaseA(v0, Ar, Ai);
    gT_write(T, Ar, Ai, r0, r1, two, ln);

    // ---- prefetch tile1 x (latency hides under bar1 + t0 B/W/C) ----
    f2 pv[14];
    #pragma unroll
    for (int w = 0; w < 14; ++w) {
        pv[w].x = xb1[(size_t)(r0 * 14 + w) * 768];
        pv[w].y = 0.f;
    }
    if (two) {
        #pragma unroll
        for (int w = 0; w < 14; ++w) pv[w].y = xb1[(size_t)(r1 * 14 + w) * 768];
    }

    __syncthreads();                      // bar1: G(t0) visible

    float gr[14], gi[14];
    #pragma unroll
    for (int h = 0; h < 14; ++h) {
        const f2 t = up_bf16(T[(h * 8 + wv) * 64 + ln]);
        gr[h] = t.x; gi[h] = t.y;
    }
    float Qr[7], Qi[7], Rr[7], Ri[7];
    phaseBWC(gr, gi, wr, wi, Qr, Qi, Rr, Ri);

    __syncthreads();                      // bar2: G(t0) reads done (convergent)
    pT_write(T, Qr, Qi, Rr, Ri, wv, ln);
    __syncthreads();                      // bar3: P(t0) visible

    f2 a0[8], b0v[7];
    pRead(T, a0, b0v, r0, r1, two, ln);
    __syncthreads();                      // bar4: P(t0) reads done, buffer free

    // ---- tile1: A + G transpose; then t0's D + stores overlap ----
    phaseA(pv, Ar, Ai);
    gT_write(T, Ar, Ai, r0, r1, two, ln);

    phaseD(a0, b0v, ob0, r0, r1, two);    // t0 output: overlaps t1 pipeline

    __syncthreads();                      // bar5: G(t1) visible

    #pragma unroll
    for (int h = 0; h < 14; ++h) {
        const f2 t = up_bf16(T[(h * 8 + wv) * 64 + ln]);
        gr[h] = t.x; gi[h] = t.y;
    }
    phaseBWC(gr, gi, wr, wi, Qr, Qi, Rr, Ri);

    __syncthreads();                      // bar6: G(t1) reads done (convergent)
    pT_write(T, Qr, Qi, Rr, Ri, wv, ln);
    __syncthreads();                      // bar7: P(t1) visible

    pRead(T, a0, b0v, r0, r1, two, ln);
    phaseD(a0, b0v, ob1, r0, r1, two);
}

extern "C" void kernel_launch(void* const* d_in, const int* in_sizes, int n_in,
                              void* d_out, int out_size, void* d_ws, size_t ws_size,
                              hipStream_t stream) {
    const float* x   = (const float*)d_in[0];
    const float* wgt = (const float*)d_in[1];
    float*       o   = (float*)d_out;

    const int B = in_sizes[0] / (196 * 768);   // 256
    const int bhalf = B / 2;                   // 128
    dim3 grid(bhalf * CTILES), block(NT);
    gfnet_filter<<<grid, block, 0, stream>>>(x, wgt, o, bhalf);
}

// Round 13
// 54.959 us; speedup vs baseline: 1.0699x; 1.0259x over previous
//
#include <hip/hip_runtime.h>
#include <hip/hip_bf16.h>

// GFNet global filter: out = irfft2( rfft2(x) * W ), ortho norm, 14x14 spatial.
// x: (B=256, N=196, C=768) f32 ; W: (14, 8, C, 2) f32 ; out: (B, 196, C) f32.
//
// R13: CHANNEL-PAIR the entire kernel. Each lane owns channels (c, c+1) as an
// f2; every op (A/B/W/C/D, pack/unpack) is a pk-op on two independent
// channels -> total VALU issue halves with ZERO swizzle and unchanged chain
// structure (the property that made R10's A/D row-packing work, applied
// everywhere). CB 128, CTILES 6, threads halve. Global loads/stores become
// 8 B/lane (512 B/wave) -> wider nt-store stream.
// Rationale: R9-R12 wall pinned at 56.4-56.8us across busy 31.6-42us,
// barriers 3-7, 1- and 2-tile pipelines -> only total-issue scaling left.
//
// LDS 57344 B (uint2 per (h,u,lane)); 2 blocks/CU (R12: residency ceiling is
// not the binding constraint). W-multiply FUSED into the B k-loop with JIT
// per-k float4 weight loads (L2-resident) so E/O and H never coexist ->
// peak live ~115 VGPR under the (512,2) budget ~128.
// Spill tripwire: WRITE_SIZE must equal 150.5 MB.
//
// Memory structure from R9: bf16-packed single-round LDS transposes,
// 3 barriers, non-temporal output stores (out-stream was evicting x from LLC).

static constexpr int CB     = 128;        // channels per block (2 per lane)
static constexpr int NT     = 512;
static constexpr int CTILES = 768 / CB;   // 6

typedef float f2 __attribute__((ext_vector_type(2)));

// cos/sin(2*pi*k/14)
static constexpr float C14[14] = {
     1.0f,
     0.90096886790241915f,  0.62348980185873359f,  0.22252093395631445f,
    -0.22252093395631434f, -0.62348980185873348f, -0.90096886790241915f,
    -1.0f,
    -0.90096886790241926f, -0.62348980185873371f, -0.22252093395631456f,
     0.22252093395631423f,  0.62348980185873337f,  0.90096886790241904f
};
static constexpr float S14[14] = {
     0.0f,
     0.43388373911755812f,  0.78183148246802980f,  0.97492791218182362f,
     0.97492791218182362f,  0.78183148246802991f,  0.43388373911755823f,
     0.0f,
    -0.43388373911755806f, -0.78183148246802958f, -0.97492791218182362f,
    -0.97492791218182373f, -0.78183148246802991f, -0.43388373911755834f
};

__device__ __forceinline__ f2 mk2(float a, float b) { f2 r; r.x = a; r.y = b; return r; }
__device__ __forceinline__ f2 sp2(float a)          { f2 r; r.x = a; r.y = a; return r; }
__device__ __forceinline__ f2 fma2(f2 a, float c, f2 acc) {
    return __builtin_elementwise_fma(a, sp2(c), acc);
}
__device__ __forceinline__ f2 fmav(f2 a, f2 b, f2 acc) {
    return __builtin_elementwise_fma(a, b, acc);
}

__device__ __forceinline__ uint32_t pk1(float re, float im) {
    union { __hip_bfloat162 h2; uint32_t u; } cv;
    cv.h2 = __float22bfloat162_rn(make_float2(re, im));
    return cv.u;
}
__device__ __forceinline__ uint2 pk2(f2 re, f2 im) {
    uint2 r; r.x = pk1(re.x, im.x); r.y = pk1(re.y, im.y); return r;
}
__device__ __forceinline__ f2 up_lo(uint2 v) {   // re of both channels
    return mk2(__uint_as_float(v.x << 16), __uint_as_float(v.y << 16));
}
__device__ __forceinline__ f2 up_hi(uint2 v) {   // im of both channels
    return mk2(__uint_as_float(v.x & 0xffff0000u), __uint_as_float(v.y & 0xffff0000u));
}

// ---------------- phase A: rfft along w for one row (channel-pair lanes) ----------------
__device__ __forceinline__ void phaseA(const f2 v[14], f2 Ar[8], f2 Ai[7]) {
    f2 s[7], d[7];
    #pragma unroll
    for (int j = 1; j <= 6; ++j) { s[j] = v[j] + v[14 - j]; d[j] = v[j] - v[14 - j]; }
    const f2 p = v[0] + v[7], q = v[0] - v[7];
    Ar[0] = p + s[1] + s[2] + s[3] + s[4] + s[5] + s[6];
    Ar[7] = q - s[1] + s[2] - s[3] + s[4] - s[5] + s[6];
    #pragma unroll
    for (int u = 1; u <= 6; ++u) {
        f2 re = (u & 1) ? q : p;
        f2 im = sp2(0.f);
        #pragma unroll
        for (int j = 1; j <= 6; ++j) {
            re = fma2(s[j],  C14[(u * j) % 14], re);
            im = fma2(d[j], -S14[(u * j) % 14], im);
        }
        Ar[u] = re; Ai[u] = im;
    }
}

// ---------------- phase D + nt stores for one row ----------------
__device__ __forceinline__ void phaseD_row(const uint2* T2, float* ob, int row, int ln) {
    f2 a0[8], b0v[7];
    #pragma unroll
    for (int v = 0; v < 8; ++v) {
        const uint2 t = T2[(row * 8 + v) * 64 + ln];
        const float beta = (v == 0 || v == 7) ? (1.0f / 196.0f) : (2.0f / 196.0f);
        a0[v] = up_lo(t) * sp2(beta);
        if (v >= 1 && v <= 6) b0v[v] = up_hi(t) * sp2(2.0f / 196.0f);
    }
    const f2 pp = a0[0] + a0[7], qq = a0[0] - a0[7];
    const f2 o0 = pp + a0[1] + a0[2] + a0[3] + a0[4] + a0[5] + a0[6];
    const f2 o7 = qq - a0[1] + a0[2] - a0[3] + a0[4] - a0[5] + a0[6];
    __builtin_nontemporal_store(o0, reinterpret_cast<f2*>(ob + (size_t)(row * 14 + 0) * 768));
    __builtin_nontemporal_store(o7, reinterpret_cast<f2*>(ob + (size_t)(row * 14 + 7) * 768));
    #pragma unroll
    for (int wp = 1; wp <= 6; ++wp) {
        f2 t1 = (wp & 1) ? qq : pp;
        f2 t2 = sp2(0.f);
        #pragma unroll
        for (int v = 1; v <= 6; ++v) {
            t1 = fma2(a0[v],  C14[(v * wp) % 14], t1);
            t2 = fma2(b0v[v], S14[(v * wp) % 14], t2);
        }
        __builtin_nontemporal_store(t1 - t2,
            reinterpret_cast<f2*>(ob + (size_t)(row * 14 + wp) * 768));
        __builtin_nontemporal_store(t1 + t2,
            reinterpret_cast<f2*>(ob + (size_t)(row * 14 + 14 - wp) * 768));
    }
}

__global__ __launch_bounds__(NT, 2) void gfnet_filter(
    const float* __restrict__ x,
    const float* __restrict__ wgt,
    float* __restrict__ out)
{
    // 57344 B union buffer, uint2 = packed bf16 complex for 2 channels:
    //   G round: [h=0..13][u=0..7][64]   P round: [row=0..13][v=0..7][64]
    __shared__ uint2 T2[14 * 8 * 64];

    const int bid = blockIdx.x;
    const int b   = bid / CTILES;
    const int ct  = bid - b * CTILES;
    const int c0  = ct * CB;
    const int tid = threadIdx.x;
    const int wv  = tid >> 6;
    const int ln  = tid & 63;
    const bool two = (wv < 6);
    const int r0 = wv;          // rows handled in phases A/D
    const int r1 = wv + 8;

    const float* xb = x + (size_t)b * 196 * 768 + c0 + 2 * ln;

    // ---------------- x loads (float2 per lane, both rows issued up front) ----------------
    f2 v0[14], v1[14];
    #pragma unroll
    for (int w = 0; w < 14; ++w)
        v0[w] = *reinterpret_cast<const f2*>(xb + (size_t)(r0 * 14 + w) * 768);
    if (two) {
        #pragma unroll
        for (int w = 0; w < 14; ++w)
            v1[w] = *reinterpret_cast<const f2*>(xb + (size_t)(r1 * 14 + w) * 768);
    }

    // ---------------- phase A + G transpose (packed bf16, single round) ----------------
    {
        f2 Ar[8], Ai[7];
        phaseA(v0, Ar, Ai);
        #pragma unroll
        for (int u = 0; u < 8; ++u)
            T2[(r0 * 8 + u) * 64 + ln] = pk2(Ar[u], (u >= 1 && u <= 6) ? Ai[u] : sp2(0.f));
        if (two) {
            phaseA(v1, Ar, Ai);
            #pragma unroll
            for (int u = 0; u < 8; ++u)
                T2[(r1 * 8 + u) * 64 + ln] = pk2(Ar[u], (u >= 1 && u <= 6) ? Ai[u] : sp2(0.f));
        }
    }

    __syncthreads();                    // bar1: G visible

    f2 gr[14], gi[14];
    #pragma unroll
    for (int h = 0; h < 14; ++h) {
        const uint2 t = T2[(h * 8 + wv) * 64 + ln];
        gr[h] = up_lo(t); gi[h] = up_hi(t);
    }

    // ---------------- phase B fused with weight multiply (JIT float4 weight loads) ----------------
    f2 esr[3], esi[3], edr[3], edi[3], osr[3], osi[3], odr[3], odi[3];
    #pragma unroll
    for (int i = 0; i < 3; ++i) {
        int j = 2 * (i + 1);
        esr[i] = gr[j] + gr[14 - j]; esi[i] = gi[j] + gi[14 - j];
        edr[i] = gr[j] - gr[14 - j]; edi[i] = gi[j] - gi[14 - j];
        j = 2 * i + 1;
        osr[i] = gr[j] + gr[14 - j]; osi[i] = gi[j] + gi[14 - j];
        odr[i] = gr[j] - gr[14 - j]; odi[i] = gi[j] - gi[14 - j];
    }
    const f2 g0r = gr[0], g0i = gi[0], g7r = gr[7], g7i = gi[7];

    // weights: (14, 8, C, 2); float4 covers {re(c), im(c), re(c+1), im(c+1)}
    const float* wbase = wgt + ((size_t)wv * 768 + c0 + 2 * ln) * 2;

    f2 Hr[14], Hi[14];
    #pragma unroll
    for (int k = 0; k < 7; ++k) {
        const float4 wA = *reinterpret_cast<const float4*>(wbase + (size_t)k       * (8 * 768 * 2));
        const float4 wB = *reinterpret_cast<const float4*>(wbase + (size_t)(k + 7) * (8 * 768 * 2));
        f2 er, ei, onr, oni;
        if (k == 0) {
            er  = g0r + esr[0] + esr[1] + esr[2];
            ei  = g0i + esi[0] + esi[1] + esi[2];
            onr = g7r + osr[0] + osr[1] + osr[2];
            oni = g7i + osi[0] + osi[1] + osi[2];
        } else {
            er = g0r; ei = g0i;
            #pragma unroll
            for (int i = 0; i < 3; ++i) {
                const int j = 2 * (i + 1);
                const float c = C14[(j * k) % 14], s2 = S14[(j * k) % 14];
                er = fma2(esr[i], c, er); er = fma2(edi[i],  s2, er);
                ei = fma2(esi[i], c, ei); ei = fma2(edr[i], -s2, ei);
            }
            onr = (k & 1) ? -g7r : g7r;
            oni = (k & 1) ? -g7i : g7i;
            #pragma unroll
            for (int i = 0; i < 3; ++i) {
                const int j = 2 * i + 1;
                const float c = C14[(j * k) % 14], s2 = S14[(j * k) % 14];
                onr = fma2(osr[i], c, onr); onr = fma2(odi[i],  s2, onr);
                oni = fma2(osi[i], c, oni); oni = fma2(odr[i], -s2, oni);
            }
        }
        const f2 ar = er + onr, ai = ei + oni;
        const f2 br = er - onr, bi = ei - oni;
        const f2 wAr = mk2(wA.x, wA.z), wAi = mk2(wA.y, wA.w);
        const f2 wBr = mk2(wB.x, wB.z), wBi = mk2(wB.y, wB.w);
        Hr[k]     = fmav(ar, wAr, -(ai * wAi));
        Hi[k]     = fmav(ar, wAi,   ai * wAr);
        Hr[k + 7] = fmav(br, wBr, -(bi * wBi));
        Hi[k + 7] = fmav(br, wBi,   bi * wBr);
    }

    // ---------------- phase C: P = IFFT_h(H), radix-2 + pairing ----------------
    f2 qsr[3], qsi[3], qdr[3], qdi[3], rsr[3], rsi[3], rdr[3], rdi[3];
    #pragma unroll
    for (int i = 0; i < 3; ++i) {
        int j = 2 * (i + 1);
        qsr[i] = Hr[j] + Hr[14 - j]; qsi[i] = Hi[j] + Hi[14 - j];
        qdr[i] = Hr[j] - Hr[14 - j]; qdi[i] = Hi[j] - Hi[14 - j];
        j = 2 * i + 1;
        rsr[i] = Hr[j] + Hr[14 - j]; rsi[i] = Hi[j] + Hi[14 - j];
        rdr[i] = Hr[j] - Hr[14 - j]; rdi[i] = Hi[j] - Hi[14 - j];
    }
    f2 Qr[7], Qi[7], Rr[7], Ri[7];
    Qr[0] = Hr[0] + qsr[0] + qsr[1] + qsr[2];
    Qi[0] = Hi[0] + qsi[0] + qsi[1] + qsi[2];
    Rr[0] = Hr[7] + rsr[0] + rsr[1] + rsr[2];
    Ri[0] = Hi[7] + rsi[0] + rsi[1] + rsi[2];
    #pragma unroll
    for (int m = 1; m <= 6; ++m) {
        f2 qr = Hr[0], qi2 = Hi[0];
        #pragma unroll
        for (int i = 0; i < 3; ++i) {
            const int j = 2 * (i + 1);
            const float c = C14[(j * m) % 14], s2 = S14[(j * m) % 14];
            qr  = fma2(qsr[i], c, qr);  qr  = fma2(qdi[i], -s2, qr);
            qi2 = fma2(qsi[i], c, qi2); qi2 = fma2(qdr[i],  s2, qi2);
        }
        Qr[m] = qr; Qi[m] = qi2;
        f2 rr = (m & 1) ? -Hr[7] : Hr[7];
        f2 ri2 = (m & 1) ? -Hi[7] : Hi[7];
        #pragma unroll
        for (int i = 0; i < 3; ++i) {
            const int j = 2 * i + 1;
            const float c = C14[(j * m) % 14], s2 = S14[(j * m) % 14];
            rr  = fma2(rsr[i], c, rr);  rr  = fma2(rdi[i], -s2, rr);
            ri2 = fma2(rsi[i], c, ri2); ri2 = fma2(rdr[i],  s2, ri2);
        }
        Rr[m] = rr; Ri[m] = ri2;
    }

    __syncthreads();                    // bar2: all G reads done (convergent)

    // ---------------- P transpose (packed bf16, single round) ----------------
    #pragma unroll
    for (int m = 0; m < 7; ++m) {
        T2[(m * 8 + wv) * 64 + ln]       = pk2(Qr[m] + Rr[m], Qi[m] + Ri[m]);
        T2[((m + 7) * 8 + wv) * 64 + ln] = pk2(Qr[m] - Rr[m], Qi[m] - Ri[m]);
    }
    __syncthreads();                    // bar3: P visible

    // ---------------- phase D + nt stores ----------------
    float* ob = out + (size_t)b * 196 * 768 + c0 + 2 * ln;
    phaseD_row(T2, ob, r0, ln);
    if (two) phaseD_row(T2, ob, r1, ln);
}

extern "C" void kernel_launch(void* const* d_in, const int* in_sizes, int n_in,
                              void* d_out, int out_size, void* d_ws, size_t ws_size,
                              hipStream_t stream) {
    const float* x   = (const float*)d_in[0];
    const float* wgt = (const float*)d_in[1];
    float*       o   = (float*)d_out;

    const int B = in_sizes[0] / (196 * 768);   // 256
    dim3 grid(B * CTILES), block(NT);
    gfnet_filter<<<grid, block, 0, stream>>>(x, wgt, o);
}